// Round 10
// baseline (350.688 us; speedup 1.0000x reference)
//
#include <hip/hip_runtime.h>
#include <hip/hip_bf16.h>

typedef __hip_bfloat16 bf16;
typedef __attribute__((ext_vector_type(8))) short short8;
typedef __attribute__((ext_vector_type(4))) float f32x4;

#define AS1 __attribute__((address_space(1)))
#define AS3 __attribute__((address_space(3)))

__device__ __forceinline__ void gload_lds16(const bf16* gp, bf16* lp) {
  __builtin_amdgcn_global_load_lds((const AS1 void*)gp, (AS3 void*)lp, 16, 0, 0);
}

__device__ __forceinline__ float fast_exp2(float x) {
#if __has_builtin(__builtin_amdgcn_exp2f)
  return __builtin_amdgcn_exp2f(x);
#else
  return exp2f(x);
#endif
}

__device__ __forceinline__ void store_c(bf16* C, size_t idx, float v) { C[idx] = __float2bfloat16(v); }
__device__ __forceinline__ void store_c(float* C, size_t idx, float v) { C[idx] = v; }

struct __align__(8) b16x4 { bf16 a, b, c, d; };

// ---------------------------------------------------------------------------
// fp32 -> bf16 elementwise convert (n multiple of 1024)
// ---------------------------------------------------------------------------
__global__ void cvt_f32_bf16(const float* __restrict__ in, bf16* __restrict__ out) {
  const int i = (blockIdx.x * 256 + threadIdx.x) * 4;
  const float4 v = *(const float4*)(in + i);
  out[i + 0] = __float2bfloat16(v.x);
  out[i + 1] = __float2bfloat16(v.y);
  out[i + 2] = __float2bfloat16(v.z);
  out[i + 3] = __float2bfloat16(v.w);
}

// ---------------------------------------------------------------------------
// All 8 weight transposes (fp32 [R][C] -> bf16 [C][R]) in ONE kernel.
// ---------------------------------------------------------------------------
struct PrepArgs {
  const float* src[8];
  bf16* dst[8];
  int R[8], C[8], cum[8];
};

__global__ void prep_kernel(PrepArgs a) {
  __shared__ bf16 t[32][33];
  const int blk = blockIdx.x;
  int e = 0;
  while (e < 7 && blk >= a.cum[e]) ++e;
  const int lt = blk - (e ? a.cum[e - 1] : 0);
  const int R = a.R[e], C = a.C[e];
  const int tpr = C >> 5;
  const int bx = lt % tpr, by = lt / tpr;
  const float* in = a.src[e];
  bf16* out = a.dst[e];
  const int c0 = bx * 32, r0 = by * 32;
  const int tx = threadIdx.x, ty = threadIdx.y;
  for (int i = 0; i < 4; ++i)
    t[ty + 8 * i][tx] = __float2bfloat16(in[(size_t)(r0 + ty + 8 * i) * C + c0 + tx]);
  __syncthreads();
  for (int i = 0; i < 4; ++i)
    out[(size_t)(c0 + ty + 8 * i) * R + r0 + tx] = t[tx][ty + 8 * i];
}

// ---------------------------------------------------------------------------
// bf16 GEMM, M-tile 64 x N-tile 128 (1024 blocks at M=4096 -> 4 blocks/CU
// co-residency vs the 128-tile version's 2). MODE compile-time (r5 lesson).
//   0: C[row*ldc + cn]   4: latcat | k_rope-half split
// ---------------------------------------------------------------------------
template <typename CT, int MODE>
__global__ void gemm_bt64(const bf16* __restrict__ A, int lda,
                          const bf16* __restrict__ Bt,
                          CT* __restrict__ C, bf16* __restrict__ C2, int ldc,
                          int K)
{
  __shared__ __align__(16) bf16 As[64 * 32];
  __shared__ __align__(16) bf16 Bs[128 * 32];
  const int tid  = threadIdx.x;
  const int wave = tid >> 6, lane = tid & 63;
  const int quad = lane >> 4, l16 = lane & 15;
  const int m0 = blockIdx.y * 64, n0 = blockIdx.x * 128;
  const int wm = (wave >> 1) * 32, wn = (wave & 1) * 64;

  f32x4 acc[2][4];
#pragma unroll
  for (int i = 0; i < 2; ++i)
#pragma unroll
    for (int j = 0; j < 4; ++j) acc[i][j] = (f32x4){0.f, 0.f, 0.f, 0.f};

  const int r1  = tid >> 2;
  const int ks1 = (tid & 3) * 8;

  for (int k0 = 0; k0 < K; k0 += 32) {
    gload_lds16(A  + (size_t)(m0 + r1)      * lda + k0 + ks1, &As[tid * 8]);
    gload_lds16(Bt + (size_t)(n0 + r1)      * K   + k0 + ks1, &Bs[tid * 8]);
    gload_lds16(Bt + (size_t)(n0 + r1 + 64) * K   + k0 + ks1, &Bs[(tid + 256) * 8]);
    __syncthreads();

    short8 af[2], bf_[4];
#pragma unroll
    for (int mt = 0; mt < 2; ++mt)
      af[mt] = *(const short8*)&As[(wm + mt * 16 + l16) * 32 + quad * 8];
#pragma unroll
    for (int nt = 0; nt < 4; ++nt)
      bf_[nt] = *(const short8*)&Bs[(wn + nt * 16 + l16) * 32 + quad * 8];
#pragma unroll
    for (int mt = 0; mt < 2; ++mt)
#pragma unroll
      for (int nt = 0; nt < 4; ++nt)
        acc[mt][nt] = __builtin_amdgcn_mfma_f32_16x16x32_bf16(af[mt], bf_[nt], acc[mt][nt], 0, 0, 0);
    __syncthreads();
  }

#pragma unroll
  for (int mt = 0; mt < 2; ++mt) {
    const int row = m0 + wm + mt * 16 + quad * 4;
#pragma unroll
    for (int nt = 0; nt < 4; ++nt) {
      const int cn = n0 + wn + nt * 16 + l16;
      const f32x4 v = acc[mt][nt];
      if (MODE == 0) {
#pragma unroll
        for (int r = 0; r < 4; ++r)
          store_c(C, (size_t)(row + r) * ldc + cn, v[r]);
      } else { // MODE 4
        if (cn < 1024) {
#pragma unroll
          for (int r = 0; r < 4; ++r)
            store_c(C, (size_t)(row + r) * 1024 + cn, v[r]);
        } else {
          const int cn2 = cn - 1024;
          const int g = ((cn2 >> 6) << 7) + 64 + (cn2 & 63);
#pragma unroll
          for (int r = 0; r < 4; ++r)
            C2[(size_t)(row + r) * 2048 + g] = __float2bfloat16(v[r]);
        }
      }
    }
  }
}

// ---------------------------------------------------------------------------
// Fused up-projection GEMM: k_nope+vT (N=3072, from kv_latent) and
// q-interleave (N=2048, from q_latent) in ONE launch. K=512, lda=1024.
// grid = (40, 32): x<24 -> k_nope/vT, x>=24 -> q-interleave.
// ---------------------------------------------------------------------------
__global__ void gemm_up_fused(const bf16* __restrict__ latcat,
                              const bf16* __restrict__ wtUP,
                              const bf16* __restrict__ wtQcat,
                              bf16* __restrict__ vT, bf16* __restrict__ kfull,
                              bf16* __restrict__ qfull)
{
  const bool is2 = (blockIdx.x >= 24);
  const bf16* A  = latcat + (is2 ? 512 : 0);
  const bf16* Bt = is2 ? wtQcat : wtUP;
  const int n0 = (is2 ? (int)blockIdx.x - 24 : (int)blockIdx.x) * 128;
  const int K = 512, lda = 1024;

  __shared__ __align__(16) bf16 As[128 * 32];
  __shared__ __align__(16) bf16 Bs[128 * 32];
  const int tid  = threadIdx.x;
  const int wave = tid >> 6, lane = tid & 63;
  const int quad = lane >> 4, l16 = lane & 15;
  const int m0 = blockIdx.y * 128;
  const int wm = (wave >> 1) * 64, wn = (wave & 1) * 64;

  f32x4 acc[4][4];
#pragma unroll
  for (int i = 0; i < 4; ++i)
#pragma unroll
    for (int j = 0; j < 4; ++j) acc[i][j] = (f32x4){0.f, 0.f, 0.f, 0.f};

  const int r1  = tid >> 2;
  const int ks1 = (tid & 3) * 8;

  for (int k0 = 0; k0 < K; k0 += 32) {
    gload_lds16(A  + (size_t)(m0 + r1)      * lda + k0 + ks1, &As[tid * 8]);
    gload_lds16(A  + (size_t)(m0 + r1 + 64) * lda + k0 + ks1, &As[(tid + 256) * 8]);
    gload_lds16(Bt + (size_t)(n0 + r1)      * K   + k0 + ks1, &Bs[tid * 8]);
    gload_lds16(Bt + (size_t)(n0 + r1 + 64) * K   + k0 + ks1, &Bs[(tid + 256) * 8]);
    __syncthreads();

    short8 af[4], bf_[4];
#pragma unroll
    for (int mt = 0; mt < 4; ++mt)
      af[mt] = *(const short8*)&As[(wm + mt * 16 + l16) * 32 + quad * 8];
#pragma unroll
    for (int nt = 0; nt < 4; ++nt)
      bf_[nt] = *(const short8*)&Bs[(wn + nt * 16 + l16) * 32 + quad * 8];
#pragma unroll
    for (int mt = 0; mt < 4; ++mt)
#pragma unroll
      for (int nt = 0; nt < 4; ++nt)
        acc[mt][nt] = __builtin_amdgcn_mfma_f32_16x16x32_bf16(af[mt], bf_[nt], acc[mt][nt], 0, 0, 0);
    __syncthreads();
  }

  if (is2) {
#pragma unroll
    for (int mt = 0; mt < 4; ++mt) {
      const int row = m0 + wm + mt * 16 + quad * 4;
#pragma unroll
      for (int nt = 0; nt < 4; ++nt) {
        const int cn = n0 + wn + nt * 16 + l16;
        const int g = (((cn >> 6) & 15) << 7) + ((cn >> 10) << 6) + (cn & 63);
        const f32x4 v = acc[mt][nt];
#pragma unroll
        for (int r = 0; r < 4; ++r)
          qfull[(size_t)(row + r) * 2048 + g] = __float2bfloat16(v[r]);
      }
    }
  } else {
#pragma unroll
    for (int mt = 0; mt < 4; ++mt) {
      const int row = m0 + wm + mt * 16 + quad * 4;
#pragma unroll
      for (int nt = 0; nt < 4; ++nt) {
        const int cn = n0 + wn + nt * 16 + l16;
        const f32x4 v = acc[mt][nt];
        if (cn < 1024) {
          const int g = ((cn >> 6) << 7) + (cn & 63);
#pragma unroll
          for (int r = 0; r < 4; ++r)
            kfull[(size_t)(row + r) * 2048 + g] = __float2bfloat16(v[r]);
        } else {
          const int cn2 = cn - 1024;
          const int bb = row >> 11, s0 = row & 2047;
          b16x4 pk;
          pk.a = __float2bfloat16(v[0]); pk.b = __float2bfloat16(v[1]);
          pk.c = __float2bfloat16(v[2]); pk.d = __float2bfloat16(v[3]);
          *(b16x4*)(vT + ((size_t)(bb * 2048 + cn2)) * 2048 + s0) = pk;
        }
      }
    }
  }
}

// ---------------------------------------------------------------------------
// RoPE in place on q/k [B,S,H,128], rope half = dims 64..127, dim=64 (32 pairs)
// ---------------------------------------------------------------------------
__global__ void rope_kernel(bf16* __restrict__ q, bf16* __restrict__ k)
{
  const int idx = blockIdx.x * 256 + threadIdx.x;
  const int i = idx & 31;
  const int h = (idx >> 5) & 15;
  const int s = (idx >> 9) & 2047;
  const int b = idx >> 20;
  const size_t off = ((size_t)(b * 2048 + s)) * 2048 + h * 128 + 64;
  const float inv = fast_exp2(-(float)i * 0.41524101186092029f); // 10000^(-i/32)
  const float ang = (float)s * inv;
  const float cs = cosf(ang), sn = sinf(ang);
  {
    bf16* p = q + off;
    const float x1 = __bfloat162float(p[i]);
    const float x2 = __bfloat162float(p[i + 32]);
    p[i]      = __float2bfloat16(x1 * cs - x2 * sn);
    p[i + 32] = __float2bfloat16(x2 * cs + x1 * sn);
  }
  {
    bf16* p = k + off;
    const float x1 = __bfloat162float(p[i]);
    const float x2 = __bfloat162float(p[i + 32]);
    p[i]      = __float2bfloat16(x1 * cs - x2 * sn);
    p[i + 32] = __float2bfloat16(x2 * cs + x1 * sn);
  }
}

// ---------------------------------------------------------------------------
// Flash attention v7 (causal). r9 structure but 2 waves x 32 q-rows each
// (128-thread blocks): every K-frag / V-frag LDS read now feeds TWO MFMAs
// (one per 16-row q-set), cutting LDS ops per unit work to ~0.64x -- attn6
// was ~82% LDS-pipe-bound (136 b128-class reads/block-tile ~ 59 of 71.8 us).
// Same 64-key tiles, fixed-offset softmax, ones-MFMA row-sum, reg-prefetch,
// heavy-first 1024-block dispatch. LDS 45 KB -> 3 blocks/CU (6 waves).
// grid=(32,32), block=128.
// ---------------------------------------------------------------------------
__global__ __launch_bounds__(128, 1) void attn7_kernel(
    const bf16* __restrict__ Q, const bf16* __restrict__ Kf,
    const bf16* __restrict__ VT, bf16* __restrict__ Y)
{
  __shared__ __align__(16) bf16 Ks[64][136];     // K tile [key][d], +8 pad
  __shared__ __align__(16) bf16 VTs[128][72];    // V^T tile [d][key], +8 pad
  __shared__ __align__(16) bf16 Ps[2][32][72];   // per-wave P (32 q-rows)
  const int tid  = threadIdx.x;
  const int wave = tid >> 6, lane = tid & 63;
  const int quad = lane >> 4, l16 = lane & 15;
  const int bh = blockIdx.x;                     // fastest-varying
  const int qt = 31 - blockIdx.y;                // heavy-first
  const size_t kqbase = ((size_t)(bh >> 4) * 2048) * 2048 + (bh & 15) * 128;
  const size_t vtbase = (size_t)bh * 128 * 2048;
  const float C2 = 0.08838834764831845f * 1.4426950408889634f; // scale*log2e
  const float MNEG = -30.0f;

  short8 ones;
#pragma unroll
  for (int i = 0; i < 8; ++i) ones[i] = (short)0x3F80;   // bf16 1.0

  // staging geometry for 128 threads: K 8 instr x 8-row groups; VT 8 x 16
  const int krow = tid >> 4, kcol = (tid & 15) * 8;
  const int vrow = tid >> 3, vcol = (tid & 7) * 8;

  const int q0 = qt * 64;
  const int T = qt + 1;

  short8 qf[2][4];
#pragma unroll
  for (int set = 0; set < 2; ++set) {
    const bf16* qp = Q + kqbase + (size_t)(q0 + wave * 32 + set * 16 + l16) * 2048 + quad * 8;
#pragma unroll
    for (int kc = 0; kc < 4; ++kc) qf[set][kc] = *(const short8*)(qp + kc * 32);
  }
  f32x4 o[2][8];
#pragma unroll
  for (int s = 0; s < 2; ++s)
#pragma unroll
    for (int i = 0; i < 8; ++i) o[s][i] = (f32x4){0, 0, 0, 0};
  f32x4 lacc[2];
  lacc[0] = (f32x4){0, 0, 0, 0};
  lacc[1] = (f32x4){0, 0, 0, 0};

  short8 kg[8], vg[8];
#pragma unroll
  for (int i = 0; i < 8; ++i)
    kg[i] = *(const short8*)(Kf + kqbase + (size_t)(krow + i * 8) * 2048 + kcol);
#pragma unroll
  for (int i = 0; i < 8; ++i)
    vg[i] = *(const short8*)(VT + vtbase + (size_t)(vrow + i * 16) * 2048 + vcol);

  for (int t = 0; t < T; ++t) {
    const int k0 = t * 64;
    __syncthreads();                    // all waves done reading prev tile
#pragma unroll
    for (int i = 0; i < 8; ++i) *(short8*)&Ks[krow + i * 8][kcol] = kg[i];
#pragma unroll
    for (int i = 0; i < 8; ++i) *(short8*)&VTs[vrow + i * 16][vcol] = vg[i];
    __syncthreads();                    // tile t visible
    if (t + 1 < T) {                    // prefetch t+1 under compute
      const int kn = k0 + 64;
#pragma unroll
      for (int i = 0; i < 8; ++i)
        kg[i] = *(const short8*)(Kf + kqbase + (size_t)(kn + krow + i * 8) * 2048 + kcol);
#pragma unroll
      for (int i = 0; i < 8; ++i)
        vg[i] = *(const short8*)(VT + vtbase + (size_t)(vrow + i * 16) * 2048 + kn + vcol);
    }

    // ---- S = Q K^T : each K-frag read feeds both q-sets ----
    f32x4 sf[2][4];
#pragma unroll
    for (int s = 0; s < 2; ++s)
#pragma unroll
      for (int kt = 0; kt < 4; ++kt) sf[s][kt] = (f32x4){0, 0, 0, 0};
#pragma unroll
    for (int kc = 0; kc < 4; ++kc)
#pragma unroll
      for (int kt = 0; kt < 4; ++kt) {
        const short8 bfr = *(const short8*)&Ks[kt * 16 + l16][kc * 32 + quad * 8];
        sf[0][kt] = __builtin_amdgcn_mfma_f32_16x16x32_bf16(qf[0][kc], bfr, sf[0][kt], 0, 0, 0);
        sf[1][kt] = __builtin_amdgcn_mfma_f32_16x16x32_bf16(qf[1][kc], bfr, sf[1][kt], 0, 0, 0);
      }
    if (t == T - 1) {                   // diagonal tile: causal mask
#pragma unroll
      for (int s = 0; s < 2; ++s) {
        const int row0 = q0 + wave * 32 + s * 16 + quad * 4;
#pragma unroll
        for (int kt = 0; kt < 4; ++kt) {
          const int col = k0 + kt * 16 + l16;
#pragma unroll
          for (int r = 0; r < 4; ++r)
            sf[s][kt][r] = (col > row0 + r) ? -3e38f : sf[s][kt][r];
        }
      }
    }
    // ---- p = exp2(s*C2 - M) -> Ps ----
#pragma unroll
    for (int s = 0; s < 2; ++s)
#pragma unroll
      for (int kt = 0; kt < 4; ++kt)
#pragma unroll
        for (int r = 0; r < 4; ++r) {
          const float p = fast_exp2(__builtin_fmaf(sf[s][kt][r], C2, MNEG));
          Ps[wave][s * 16 + quad * 4 + r][kt * 16 + l16] = __float2bfloat16(p);
        }
    asm volatile("s_waitcnt lgkmcnt(0)" ::: "memory");
    // ---- O += P V, l += P*1 : each V-frag read feeds both q-sets ----
#pragma unroll
    for (int kc = 0; kc < 2; ++kc) {
      const short8 ap0 = *(const short8*)&Ps[wave][l16][kc * 32 + quad * 8];
      const short8 ap1 = *(const short8*)&Ps[wave][16 + l16][kc * 32 + quad * 8];
      lacc[0] = __builtin_amdgcn_mfma_f32_16x16x32_bf16(ap0, ones, lacc[0], 0, 0, 0);
      lacc[1] = __builtin_amdgcn_mfma_f32_16x16x32_bf16(ap1, ones, lacc[1], 0, 0, 0);
#pragma unroll
      for (int dt = 0; dt < 8; ++dt) {
        const short8 vb = *(const short8*)&VTs[dt * 16 + l16][kc * 32 + quad * 8];
        o[0][dt] = __builtin_amdgcn_mfma_f32_16x16x32_bf16(ap0, vb, o[0][dt], 0, 0, 0);
        o[1][dt] = __builtin_amdgcn_mfma_f32_16x16x32_bf16(ap1, vb, o[1][dt], 0, 0, 0);
      }
    }
  }

#pragma unroll
  for (int s = 0; s < 2; ++s) {
    const int row0 = q0 + wave * 32 + s * 16 + quad * 4;
#pragma unroll
    for (int r = 0; r < 4; ++r) {
      const float inv = 1.0f / lacc[s][r];
#pragma unroll
      for (int dt = 0; dt < 8; ++dt)
        Y[kqbase + (size_t)(row0 + r) * 2048 + dt * 16 + l16] = __float2bfloat16(o[s][dt][r] * inv);
    }
  }
}

// ---------------------------------------------------------------------------
extern "C" void kernel_launch(void* const* d_in, const int* in_sizes, int n_in,
                              void* d_out, int out_size, void* d_ws, size_t ws_size,
                              hipStream_t stream)
{
  const float* x      = (const float*)d_in[0];
  const float* Wkvd   = (const float*)d_in[1];
  const float* Wqd    = (const float*)d_in[2];
  const float* Wku    = (const float*)d_in[3];
  const float* Wqu    = (const float*)d_in[4];
  const float* Wvu    = (const float*)d_in[5];
  const float* Wropek = (const float*)d_in[6];
  const float* Wropeq = (const float*)d_in[7];
  const float* Wo     = (const float*)d_in[8];

  char* ws = (char*)d_ws;
  size_t off = 0;
  auto alloc = [&](size_t elems) {
    bf16* p = (bf16*)(ws + off);
    off += ((elems * sizeof(bf16) + 255) & ~(size_t)255);
    return p;
  };
  // Region A — dead before attn; ybuf (16 MB) aliases it.
  bf16* wtX    = alloc((size_t)2048 * 2048); // Wkvd^T | Wqd^T | Wropek^T
  bf16* wtUP   = alloc((size_t)3072 * 512);  // Wku^T | Wvu^T
  bf16* wtQcat = alloc((size_t)2048 * 512);  // Wqu^T | Wropeq^T
  bf16* latcat = alloc((size_t)4096 * 1024);
  // end region A (21 MB)
  bf16* wt_o   = alloc((size_t)2048 * 2048);
  bf16* xbf    = alloc((size_t)4096 * 2048);
  bf16* qfull  = alloc((size_t)4096 * 2048);
  bf16* kfull  = alloc((size_t)4096 * 2048);
  bf16* ybuf   = (bf16*)ws;
  bf16* vT     = (bf16*)d_out;
  (void)ws_size; (void)in_sizes; (void)n_in; (void)out_size;

  cvt_f32_bf16<<<8192, 256, 0, stream>>>(x, xbf);

  PrepArgs pa;
  const float* srcs[8] = {Wkvd, Wqd, Wropek, Wku, Wvu, Wqu, Wropeq, Wo};
  bf16* dsts[8] = {wtX, wtX + (size_t)512 * 2048, wtX + (size_t)1024 * 2048,
                   wtUP, wtUP + (size_t)1024 * 512,
                   wtQcat, wtQcat + (size_t)1024 * 512, wt_o};
  const int Rs[8] = {2048, 2048, 2048, 512, 512, 512, 512, 2048};
  const int Cs[8] = {512, 512, 1024, 1024, 2048, 1024, 1024, 2048};
  int cum = 0;
  for (int e = 0; e < 8; ++e) {
    pa.src[e] = srcs[e]; pa.dst[e] = dsts[e]; pa.R[e] = Rs[e]; pa.C[e] = Cs[e];
    cum += (Rs[e] >> 5) * (Cs[e] >> 5);
    pa.cum[e] = cum;
  }
  prep_kernel<<<cum, dim3(32, 8), 0, stream>>>(pa);

  // latcat = x @ [W_kv_d | W_q_d]  AND  k_rope = x @ W_rope_k   (M-tile 64)
  gemm_bt64<bf16, 4><<<dim3(16, 64), 256, 0, stream>>>(xbf, 2048, wtX, latcat, kfull, 1024, 2048);
  // k_nope+vT AND q-interleave, fused single launch
  gemm_up_fused<<<dim3(40, 32), 256, 0, stream>>>(latcat, wtUP, wtQcat, vT, kfull, qfull);

  rope_kernel<<<(2 * 2048 * 16 * 32) / 256, 256, 0, stream>>>(qfull, kfull);
  attn7_kernel<<<dim3(32, 32), 128, 0, stream>>>(qfull, kfull, vT, ybuf);
  // out = y @ W_o (fp32 store, M-tile 64)
  gemm_bt64<float, 0><<<dim3(16, 64), 256, 0, stream>>>(ybuf, 2048, wt_o, (float*)d_out, (bf16*)nullptr, 2048, 2048);
}